// Round 15
// baseline (2078.906 us; speedup 1.0000x reference)
//
#include <hip/hip_runtime.h>
#include <stdint.h>

#define TT 12
#define NITERS 10
#define NCAND 1000
#define AD 6
#define BD 16
#define HD 200
#define ZD 30
#define NROWS 16000
#define NELEM 1152000u

// ws layout (u32/float offsets)
#define OFF_WSW  0u          // u32[53248]  W_all split+swizzled B-frags [hl][13][8][64][4]
#define OFF_WZSW 53248u      // u32[7168]   [Wz | Wr_h@col30] [hl][2][7][64][4]
#define OFF_MEAN 64512u      // f32[12][16][8]
#define OFF_STD  66048u      // f32[12][16][8]
#define OFF_ACT  67584u      // f32[12][16000][8]
#define OFF_RET  1603584u    // f32[16000]

typedef __attribute__((ext_vector_type(8))) short short8v;
typedef __attribute__((ext_vector_type(4))) float f32x4;

// ---------------- threefry2x32 (JAX-exact) ----------------
__host__ __device__ __forceinline__ uint32_t tf_rotl(uint32_t x, int r) {
  return (x << r) | (x >> (32 - r));
}
__host__ __device__ __forceinline__ void tf2x32(uint32_t k0, uint32_t k1,
                                                uint32_t& x0, uint32_t& x1) {
  uint32_t k2 = k0 ^ k1 ^ 0x1BD11BDAu;
  x0 += k0; x1 += k1;
  x0 += x1; x1 = tf_rotl(x1, 13); x1 ^= x0;
  x0 += x1; x1 = tf_rotl(x1, 15); x1 ^= x0;
  x0 += x1; x1 = tf_rotl(x1, 26); x1 ^= x0;
  x0 += x1; x1 = tf_rotl(x1,  6); x1 ^= x0;
  x0 += k1; x1 += k2 + 1u;
  x0 += x1; x1 = tf_rotl(x1, 17); x1 ^= x0;
  x0 += x1; x1 = tf_rotl(x1, 29); x1 ^= x0;
  x0 += x1; x1 = tf_rotl(x1, 16); x1 ^= x0;
  x0 += x1; x1 = tf_rotl(x1, 24); x1 ^= x0;
  x0 += k2; x1 += k0 + 2u;
  x0 += x1; x1 = tf_rotl(x1, 13); x1 ^= x0;
  x0 += x1; x1 = tf_rotl(x1, 15); x1 ^= x0;
  x0 += x1; x1 = tf_rotl(x1, 26); x1 ^= x0;
  x0 += x1; x1 = tf_rotl(x1,  6); x1 ^= x0;
  x0 += k0; x1 += k1 + 3u;
  x0 += x1; x1 = tf_rotl(x1, 17); x1 ^= x0;
  x0 += x1; x1 = tf_rotl(x1, 29); x1 ^= x0;
  x0 += x1; x1 = tf_rotl(x1, 16); x1 ^= x0;
  x0 += x1; x1 = tf_rotl(x1, 24); x1 ^= x0;
  x0 += k1; x1 += k2 + 4u;
  x0 += x1; x1 = tf_rotl(x1, 13); x1 ^= x0;
  x0 += x1; x1 = tf_rotl(x1, 15); x1 ^= x0;
  x0 += x1; x1 = tf_rotl(x1, 26); x1 ^= x0;
  x0 += x1; x1 = tf_rotl(x1,  6); x1 ^= x0;
  x0 += k2; x1 += k0 + 5u;
}

__device__ __forceinline__ float bits_to_normal(uint32_t bits) {
  uint32_t fb = (bits >> 9) | 0x3F800000u;
  float f = __uint_as_float(fb) - 1.0f;          // [0,1)
  float u = f * 2.0f - 0.99999994f;
  u = fmaxf(-0.99999994f, u);
  float w = -log1pf(-u * u);
  float p;
  if (w < 5.0f) {
    w = w - 2.5f;
    p = 2.81022636e-08f;
    p = fmaf(p, w, 3.43273939e-07f);
    p = fmaf(p, w, -3.5233877e-06f);
    p = fmaf(p, w, -4.39150654e-06f);
    p = fmaf(p, w, 0.00021858087f);
    p = fmaf(p, w, -0.00125372503f);
    p = fmaf(p, w, -0.00417768164f);
    p = fmaf(p, w, 0.246640727f);
    p = fmaf(p, w, 1.50140941f);
  } else {
    w = sqrtf(w) - 3.0f;
    p = -0.000200214257f;
    p = fmaf(p, w, 0.000100950558f);
    p = fmaf(p, w, 0.00134934322f);
    p = fmaf(p, w, -0.00367342844f);
    p = fmaf(p, w, 0.00573950773f);
    p = fmaf(p, w, -0.0076224613f);
    p = fmaf(p, w, 0.00943887047f);
    p = fmaf(p, w, 1.00167406f);
    p = fmaf(p, w, 2.83297682f);
  }
  return 1.41421354f * (p * u);
}

// bf16 round-to-nearest-even (returns 16-bit pattern)
__device__ __forceinline__ uint32_t bf16rne(float x) {
  uint32_t u = __float_as_uint(x);
  return (u + 0x7FFFu + ((u >> 16) & 1u)) >> 16;
}

// fast tanh: Eigen/XLA-style rational approx x*P(x2)/Q(x2), |err|~1e-7 rel.
__device__ __forceinline__ float fast_tanh(float x) {
  x = fmaxf(-7.90531110763549805f, fminf(7.90531110763549805f, x));
  float x2 = x * x;
  float p = -2.76076847742355e-16f;
  p = fmaf(x2, p, 2.00018790482477e-13f);
  p = fmaf(x2, p, -8.60467152213735e-11f);
  p = fmaf(x2, p, 5.12229709037114e-08f);
  p = fmaf(x2, p, 1.48572235717979e-05f);
  p = fmaf(x2, p, 6.37261928875436e-04f);
  p = fmaf(x2, p, 4.89352455891786e-03f);
  p = x * p;
  float q = 1.19825839466702e-06f;
  q = fmaf(x2, q, 1.18534705686654e-04f);
  q = fmaf(x2, q, 2.26843774817441e-03f);
  q = fmaf(x2, q, 4.89352518554385e-03f);
  return p * __builtin_amdgcn_rcpf(q);
}

// ---------------- prep: split+swizzle weights; init mean/std ----------------
__global__ __launch_bounds__(256) void k_prep(const float* Wb, const float* Ws_,
                                              const float* Wa, const float* Wz,
                                              const float* Wr, float* ws) {
  int i = blockIdx.x * 256 + threadIdx.x;
  uint32_t* wsu = (uint32_t*)ws;
  if (i < 53248) {
    int d = i & 3; int t = i >> 2;
    int lane = t & 63; t >>= 6;
    int ks = t & 7; t >>= 3;
    int nt = t % 13; int hl = t / 13;
    int col = nt * 16 + (lane & 15);
    int kb = ks * 32 + (lane >> 4) * 8 + d * 2;
    uint32_t out = 0;
    for (int e = 0; e < 2; ++e) {
      int k = kb + e;
      float v = 0.f;
      if (col < 200) {
        if (k < 200)      v = Wb[k * 200 + col];
        else if (k < 230) v = Ws_[(k - 200) * 200 + col];
        else if (k < 236) v = Wa[(k - 230) * 200 + col];
      }
      uint32_t hi = bf16rne(v);
      float hf = __uint_as_float(hi << 16);
      uint32_t lo = bf16rne(v - hf);
      uint32_t bits = (hl == 0) ? hi : lo;
      out |= (bits & 0xFFFFu) << (16 * e);
    }
    wsu[OFF_WSW + i] = out;
  } else if (i < 60416) {
    int j = i - 53248;
    int d = j & 3; int t = j >> 2;
    int lane = t & 63; t >>= 6;
    int ks = t % 7; t /= 7;
    int nt = t & 1; int hl = t >> 1;
    int col = nt * 16 + (lane & 15);
    int kb = ks * 32 + (lane >> 4) * 8 + d * 2;
    uint32_t out = 0;
    for (int e = 0; e < 2; ++e) {
      int k = kb + e;
      float v = 0.f;
      if (k < 200) {
        if (col < 30)       v = Wz[k * 30 + col];
        else if (col == 30) v = Wr[k];       // merged reward: h·Wr via col 30
      }
      uint32_t hi = bf16rne(v);
      float hf = __uint_as_float(hi << 16);
      uint32_t lo = bf16rne(v - hf);
      uint32_t bits = (hl == 0) ? hi : lo;
      out |= (bits & 0xFFFFu) << (16 * e);
    }
    wsu[OFF_WZSW + j] = out;
  } else if (i >= 64512 && i < 66048) {
    ws[i] = 0.f;   // mean
  } else if (i >= 66048 && i < 67584) {
    ws[i] = 1.f;   // std
  }
}

// ---------------- full 12-step rollout via split-bf16 MFMA (3-pass) ----------------
// R14 structure verbatim (proven absmax 0.0). New: PERSISTENT B-FRAGMENTS —
// stage-1 ks 0..2 and all stage-2 B-frags preloaded into registers before the
// t-loop (they are step/iteration-invariant) — pure data-flow change, same
// bits, removes ~44% of per-step L2 B-load latency exposure.
// Phases: [B0] s1-read |B1| h-write |B2| s2-read |B3| s-write+act(t+1) [B0].
__global__ __launch_bounds__(256) void k_roll(float* __restrict__ ws,
                                              const float* __restrict__ belief,
                                              const float* __restrict__ state,
                                              const float* __restrict__ bbp,
                                              const float* __restrict__ bzp,
                                              const float* __restrict__ brp,
                                              const float* __restrict__ wrp,
                                              uint32_t f0, uint32_t f1) {
  __shared__ unsigned short xh[32 * 280];   // bf16 hi
  __shared__ unsigned short xl[32 * 280];   // bf16 lo
  __shared__ float rp[4][16];               // per-wave reward partials

  const int tid = threadIdx.x;
  const int wv = tid >> 6;
  const int ln = tid & 63;
  const int r = ln & 15;
  const int kh = ln >> 4;
  const int grow0 = blockIdx.x * 32;
  const uint32_t* __restrict__ wsu = (const uint32_t*)ws;

  // stage-1 role (R7/R10 mapping)
  const int NT  = (wv == 0) ? 4 : 3;
  const int ntb = (wv == 0) ? 0 : (1 + wv * 3);
  // stage-2 role
  const int m2 = wv & 1, j2 = wv >> 1;

  float bbv[4];
#pragma unroll
  for (int j = 0; j < 4; ++j) {
    int col = (ntb + j) * 16 + r;
    bbv[j] = (j < NT && col < 200) ? bbp[col] : 0.f;
  }
  float bzz;
  {
    int col = j2 * 16 + r;
    bzz = (col < 30) ? bzp[col] : 0.f;
  }
  const float wr_s = (j2 == 0) ? wrp[200 + r] : ((r < 14) ? wrp[216 + r] : 0.f);
  const float br0 = brp[0];

  // ---- persistent B-fragments (step-invariant; loaded once) ----
  short8v B1h[4][3], B1l[4][3];
#pragma unroll
  for (int j = 0; j < 4; ++j) {
#pragma unroll
    for (int ks = 0; ks < 3; ++ks) {
      if (j < NT) {
        const int nt = ntb + j;
        B1h[j][ks] = *(const short8v*)(wsu + OFF_WSW + (((0 * 13 + nt) * 8 + ks) * 64 + ln) * 4);
        B1l[j][ks] = *(const short8v*)(wsu + OFF_WSW + (((1 * 13 + nt) * 8 + ks) * 64 + ln) * 4);
      } else {
        B1h[j][ks] = short8v{0,0,0,0,0,0,0,0};
        B1l[j][ks] = short8v{0,0,0,0,0,0,0,0};
      }
    }
  }
  short8v B2h[7], B2l[7];
#pragma unroll
  for (int ks = 0; ks < 7; ++ks) {
    B2h[ks] = *(const short8v*)(wsu + OFF_WZSW + (((0 * 2 + j2) * 7 + ks) * 64 + ln) * 4);
    B2l[ks] = *(const short8v*)(wsu + OFF_WZSW + (((1 * 2 + j2) * 7 + ks) * 64 + ln) * 4);
  }

  // init x: k<200 belief, 200..230 state, 236..256 zero (230..236 by act-gen)
  for (int idx = tid; idx < 32 * 256; idx += 256) {
    int row = idx >> 8, k = idx & 255;
    if (k >= 230 && k < 236) continue;      // actions written below (disjoint)
    int b = (grow0 + row) / 1000;
    float v = 0.f;
    if (k < 200) v = belief[b * 200 + k];
    else if (k < 230) v = state[b * 30 + (k - 200)];
    uint32_t hi = bf16rne(v);
    float hf = __uint_as_float(hi << 16);
    uint32_t lo = bf16rne(v - hf);
    xh[row * 280 + k] = (unsigned short)hi;
    xl[row * 280 + k] = (unsigned short)lo;
  }
  // t=0 actions: threefry in-kernel (bit-identical to reference PRNG)
  if (tid < 192) {
    int row = tid / 6, a = tid - row * 6;
    int growR = grow0 + row;
    int b = growR / 1000;
    uint32_t idx = (uint32_t)growR * 6u + (uint32_t)a;   // t=0
    uint32_t y0 = 0u, y1 = idx;
    tf2x32(f0, f1, y0, y1);
    float z = bits_to_normal(y0 ^ y1);
    float mu = ws[OFF_MEAN + (size_t)b * 8 + a];
    float sd = ws[OFF_STD + (size_t)b * 8 + a];
    float v = fmaf(sd, z, mu);
    ws[OFF_ACT + (size_t)growR * 8 + a] = v;
    uint32_t hi = bf16rne(v);
    float hf = __uint_as_float(hi << 16);
    uint32_t lo = bf16rne(v - hf);
    xh[row * 280 + 230 + a] = (unsigned short)hi;
    xl[row * 280 + 230 + a] = (unsigned short)lo;
  }
  __syncthreads();                           // B0(t=0): all writes complete

  float rps[4] = {0.f, 0.f, 0.f, 0.f};

#pragma unroll 1
  for (int t = 0; t < TT; ++t) {
    // ---- Phase A: stage 1 reads; h = x @ W_all + bb; 2 M-tiles x NT N-tiles ----
    f32x4 acc[2][4];
#pragma unroll
    for (int m = 0; m < 2; ++m)
#pragma unroll
      for (int j = 0; j < 4; ++j) {
        f32x4 c = {bbv[j], bbv[j], bbv[j], bbv[j]};
        acc[m][j] = c;
      }

#pragma unroll
    for (int ks = 0; ks < 8; ++ks) {
      short8v Ah[2], Al[2];
      const int kbase = ks * 32 + kh * 8;
#pragma unroll
      for (int m = 0; m < 2; ++m) {
        int off = (m * 16 + r) * 280 + kbase;
        Ah[m] = *(const short8v*)&xh[off];
        Al[m] = *(const short8v*)&xl[off];
      }
#pragma unroll
      for (int j = 0; j < 4; ++j) {
        if (j < NT) {
          short8v Bh, Bl;
          if (ks < 3) {                      // compile-time (unrolled): static idx
            Bh = B1h[j][ks];
            Bl = B1l[j][ks];
          } else {
            const int nt = ntb + j;
            Bh = *(const short8v*)(wsu + OFF_WSW + (((0 * 13 + nt) * 8 + ks) * 64 + ln) * 4);
            Bl = *(const short8v*)(wsu + OFF_WSW + (((1 * 13 + nt) * 8 + ks) * 64 + ln) * 4);
          }
#pragma unroll
          for (int m = 0; m < 2; ++m) {
            f32x4 c = acc[m][j];
            c = __builtin_amdgcn_mfma_f32_16x16x32_bf16(Ah[m], Bl, c, 0, 0, 0);
            c = __builtin_amdgcn_mfma_f32_16x16x32_bf16(Al[m], Bh, c, 0, 0, 0);
            c = __builtin_amdgcn_mfma_f32_16x16x32_bf16(Ah[m], Bh, c, 0, 0, 0);
            acc[m][j] = c;
          }
        }
      }
    }
    __syncthreads();                         // B1: all stage-1 reads done

    // ---- Phase B: h epilogue writes (D: row=(ln>>4)*4+reg, col=ln&15) ----
#pragma unroll
    for (int j = 0; j < 4; ++j) {
      int col = (ntb + j) * 16 + r;
      if (j < NT && col < 200) {
#pragma unroll
        for (int m = 0; m < 2; ++m) {
#pragma unroll
          for (int reg = 0; reg < 4; ++reg) {
            int row = m * 16 + kh * 4 + reg;
            float h = fast_tanh(acc[m][j][reg]);
            uint32_t hi = bf16rne(h);
            float hf = __uint_as_float(hi << 16);
            uint32_t lo = bf16rne(h - hf);
            xh[row * 280 + col] = (unsigned short)hi;
            xl[row * 280 + col] = (unsigned short)lo;
          }
        }
      }
    }
    __syncthreads();                         // B2: h writes complete

    // ---- Phase C: stage 2 reads; s-preact = h @ [Wz|Wr] + bz; unit (m2,j2) ----
    f32x4 acc2 = {bzz, bzz, bzz, bzz};
#pragma unroll
    for (int ks = 0; ks < 7; ++ks) {         // K=224; k>=200 weights are 0
      int off = (m2 * 16 + r) * 280 + ks * 32 + kh * 8;
      short8v Ah2 = *(const short8v*)&xh[off];
      short8v Al2 = *(const short8v*)&xl[off];
      acc2 = __builtin_amdgcn_mfma_f32_16x16x32_bf16(Ah2, B2l[ks], acc2, 0, 0, 0);
      acc2 = __builtin_amdgcn_mfma_f32_16x16x32_bf16(Al2, B2h[ks], acc2, 0, 0, 0);
      acc2 = __builtin_amdgcn_mfma_f32_16x16x32_bf16(Ah2, B2h[ks], acc2, 0, 0, 0);
    }
    __syncthreads();                         // B3: all stage-2 reads done

    // ---- Phase D: s writes + reward partial + act(t+1) gen/write ----
    if (j2 == 0) {
#pragma unroll
      for (int reg = 0; reg < 4; ++reg) {
        int row = m2 * 16 + kh * 4 + reg;
        float s = fast_tanh(acc2[reg]);
        uint32_t hi = bf16rne(s);
        float hf = __uint_as_float(hi << 16);
        uint32_t lo = bf16rne(s - hf);
        xh[row * 280 + 200 + r] = (unsigned short)hi;
        xl[row * 280 + 200 + r] = (unsigned short)lo;
        rps[reg] = fmaf(s, wr_s, rps[reg]);
      }
    } else {
      if (r < 14) {
#pragma unroll
        for (int reg = 0; reg < 4; ++reg) {
          int row = m2 * 16 + kh * 4 + reg;
          float s = fast_tanh(acc2[reg]);
          uint32_t hi = bf16rne(s);
          float hf = __uint_as_float(hi << 16);
          uint32_t lo = bf16rne(s - hf);
          xh[row * 280 + 216 + r] = (unsigned short)hi;
          xl[row * 280 + 216 + r] = (unsigned short)lo;
          rps[reg] = fmaf(s, wr_s, rps[reg]);
        }
      } else if (r == 14) {
        // col 30 = h·Wr (raw, no tanh) — the merged reward term
#pragma unroll
        for (int reg = 0; reg < 4; ++reg) rps[reg] += acc2[reg];
      }
    }
    // actions for t+1 (threefry, bit-identical; write LDS + global ACT)
    if (t + 1 < TT && tid < 192) {
      int row = tid / 6, a = tid - row * 6;
      int growR = grow0 + row;
      int b = growR / 1000;
      uint32_t idx = (uint32_t)((t + 1) * NROWS + growR) * 6u + (uint32_t)a;
      uint32_t y0 = 0u, y1 = idx;
      tf2x32(f0, f1, y0, y1);
      float z = bits_to_normal(y0 ^ y1);
      float mu = ws[OFF_MEAN + (((size_t)(t + 1) * 16 + b) * 8 + a)];
      float sd = ws[OFF_STD + (((size_t)(t + 1) * 16 + b) * 8 + a)];
      float v = fmaf(sd, z, mu);
      ws[OFF_ACT + ((size_t)(t + 1) * NROWS + growR) * 8 + a] = v;
      uint32_t hi = bf16rne(v);
      float hf = __uint_as_float(hi << 16);
      uint32_t lo = bf16rne(v - hf);
      xh[row * 280 + 230 + a] = (unsigned short)hi;
      xl[row * 280 + 230 + a] = (unsigned short)lo;
    }
    __syncthreads();                         // B0(t+1): all writes complete
  }

  // final reward reduction: butterfly over 16-lane groups, combine 2 waves/row
#pragma unroll
  for (int reg = 0; reg < 4; ++reg) {
#pragma unroll
    for (int mk = 1; mk < 16; mk <<= 1)
      rps[reg] += __shfl_xor(rps[reg], mk, 64);
  }
  if (r == 0) {
#pragma unroll
    for (int reg = 0; reg < 4; ++reg)
      rp[wv][kh * 4 + reg] = rps[reg];
  }
  __syncthreads();
  if (tid < 32) {
    int mrow = tid >> 4, lrow = tid & 15;
    ws[OFF_RET + grow0 + tid] = rp[mrow][lrow] + rp[2 + mrow][lrow] + 12.0f * br0;
  }
}

// ---------------- fused selection: bitonic top-k sort + mean/std ----------------
__global__ __launch_bounds__(1024) void k_select(float* ws) {
  __shared__ float sv[1024];
  __shared__ int si[1024];
  const int b = blockIdx.x, tid = threadIdx.x;
  const float* ret = ws + OFF_RET + b * 1000;
  sv[tid] = (tid < 1000) ? ret[tid] : -3.0e38f;
  si[tid] = tid;
  __syncthreads();
  for (int k = 2; k <= 1024; k <<= 1) {
    for (int j = k >> 1; j > 0; j >>= 1) {
      int ixj = tid ^ j;
      if (ixj > tid) {
        float v1 = sv[tid], v2 = sv[ixj];
        int i1 = si[tid], i2 = si[ixj];
        bool gt = (v1 < v2) || (v1 == v2 && i1 > i2);
        bool up = ((tid & k) == 0);
        if (up ? gt : !gt) {
          sv[tid] = v2; sv[ixj] = v1;
          si[tid] = i2; si[ixj] = i1;
        }
      }
      __syncthreads();
    }
  }
  // mean/std per (t,a): one wave per unit (verbatim k_meanstd reduction)
  const int wvS = tid >> 6, lnS = tid & 63;
  for (int u = wvS; u < 72; u += 16) {
    const int t = u / 6, a = u - t * 6;
    const float* act = ws + OFF_ACT + (size_t)t * NROWS * 8;
    const bool h2 = (lnS < 36);
    int c1 = si[lnS];
    float x1 = act[((size_t)b * 1000 + c1) * 8 + a];
    float x2 = 0.f;
    if (h2) { int cc = si[lnS + 64]; x2 = act[((size_t)b * 1000 + cc) * 8 + a]; }
    float s = x1 + x2;
#pragma unroll
    for (int m = 1; m < 64; m <<= 1) s += __shfl_xor(s, m, 64);
    const float mean = s / 100.0f;
    float d = x1 - mean; float qq = d * d;
    if (h2) { float d2 = x2 - mean; qq += d2 * d2; }
#pragma unroll
    for (int m = 1; m < 64; m <<= 1) qq += __shfl_xor(qq, m, 64);
    if (lnS == 0) {
      ws[OFF_MEAN + ((size_t)t * 16 + b) * 8 + a] = mean;
      ws[OFF_STD  + ((size_t)t * 16 + b) * 8 + a] = sqrtf(qq / 100.0f);
    }
  }
}

__global__ void k_out(const float* ws, float* out) {
  int i = threadIdx.x;
  if (i < 96) out[i] = ws[OFF_MEAN + (i / 6) * 8 + (i % 6)];
}

extern "C" void kernel_launch(void* const* d_in, const int* in_sizes, int n_in,
                              void* d_out, int out_size, void* d_ws, size_t ws_size,
                              hipStream_t stream) {
  const float* belief = (const float*)d_in[0];
  const float* state  = (const float*)d_in[1];
  const float* Wb  = (const float*)d_in[2];
  const float* Ws_ = (const float*)d_in[3];
  const float* Wa  = (const float*)d_in[4];
  const float* bb  = (const float*)d_in[5];
  const float* Wz  = (const float*)d_in[6];
  const float* bz  = (const float*)d_in[7];
  const float* Wr  = (const float*)d_in[8];
  const float* br  = (const float*)d_in[9];
  float* ws = (float*)d_ws;   // needs ~6.5 MB

  k_prep<<<264, 256, 0, stream>>>(Wb, Ws_, Wa, Wz, Wr, ws);

  for (int it = 0; it < NITERS; ++it) {
    uint32_t f0 = 0u, f1 = (uint32_t)it;
    tf2x32(0u, 42u, f0, f1);
    k_roll<<<500, 256, 0, stream>>>(ws, belief, state, bb, bz, br, Wr, f0, f1);
    k_select<<<16, 1024, 0, stream>>>(ws);
  }
  k_out<<<1, 128, 0, stream>>>(ws, (float*)d_out);
}

// Round 17
// 1507.840 us; speedup vs baseline: 1.3787x; 1.3787x over previous
//
#include <hip/hip_runtime.h>
#include <stdint.h>

#define TT 12
#define NITERS 10
#define NCAND 1000
#define AD 6
#define BD 16
#define HD 200
#define ZD 30
#define NROWS 16000
#define NELEM 1152000u
#define XS (32 * 280)        // per-buffer LDS x stride (elements)

// ws layout (u32/float offsets)
#define OFF_WSW  0u          // u32[53248]  W_all split+swizzled B-frags [hl][13][8][64][4]
#define OFF_WZSW 53248u      // u32[7168]   [Wz | Wr_h@col30] [hl][2][7][64][4]
#define OFF_MEAN 64512u      // f32[12][16][8]
#define OFF_STD  66048u      // f32[12][16][8]
#define OFF_ACT  67584u      // f32[12][16000][8]
#define OFF_RET  1603584u    // f32[16000]

typedef __attribute__((ext_vector_type(8))) short short8v;
typedef __attribute__((ext_vector_type(4))) float f32x4;

// ---------------- threefry2x32 (JAX-exact) ----------------
__host__ __device__ __forceinline__ uint32_t tf_rotl(uint32_t x, int r) {
  return (x << r) | (x >> (32 - r));
}
__host__ __device__ __forceinline__ void tf2x32(uint32_t k0, uint32_t k1,
                                                uint32_t& x0, uint32_t& x1) {
  uint32_t k2 = k0 ^ k1 ^ 0x1BD11BDAu;
  x0 += k0; x1 += k1;
  x0 += x1; x1 = tf_rotl(x1, 13); x1 ^= x0;
  x0 += x1; x1 = tf_rotl(x1, 15); x1 ^= x0;
  x0 += x1; x1 = tf_rotl(x1, 26); x1 ^= x0;
  x0 += x1; x1 = tf_rotl(x1,  6); x1 ^= x0;
  x0 += k1; x1 += k2 + 1u;
  x0 += x1; x1 = tf_rotl(x1, 17); x1 ^= x0;
  x0 += x1; x1 = tf_rotl(x1, 29); x1 ^= x0;
  x0 += x1; x1 = tf_rotl(x1, 16); x1 ^= x0;
  x0 += x1; x1 = tf_rotl(x1, 24); x1 ^= x0;
  x0 += k2; x1 += k0 + 2u;
  x0 += x1; x1 = tf_rotl(x1, 13); x1 ^= x0;
  x0 += x1; x1 = tf_rotl(x1, 15); x1 ^= x0;
  x0 += x1; x1 = tf_rotl(x1, 26); x1 ^= x0;
  x0 += x1; x1 = tf_rotl(x1,  6); x1 ^= x0;
  x0 += k0; x1 += k1 + 3u;
  x0 += x1; x1 = tf_rotl(x1, 17); x1 ^= x0;
  x0 += x1; x1 = tf_rotl(x1, 29); x1 ^= x0;
  x0 += x1; x1 = tf_rotl(x1, 16); x1 ^= x0;
  x0 += x1; x1 = tf_rotl(x1, 24); x1 ^= x0;
  x0 += k1; x1 += k2 + 4u;
  x0 += x1; x1 = tf_rotl(x1, 13); x1 ^= x0;
  x0 += x1; x1 = tf_rotl(x1, 15); x1 ^= x0;
  x0 += x1; x1 = tf_rotl(x1, 26); x1 ^= x0;
  x0 += x1; x1 = tf_rotl(x1,  6); x1 ^= x0;
  x0 += k2; x1 += k0 + 5u;
}

__device__ __forceinline__ float bits_to_normal(uint32_t bits) {
  uint32_t fb = (bits >> 9) | 0x3F800000u;
  float f = __uint_as_float(fb) - 1.0f;          // [0,1)
  float u = f * 2.0f - 0.99999994f;
  u = fmaxf(-0.99999994f, u);
  float w = -log1pf(-u * u);
  float p;
  if (w < 5.0f) {
    w = w - 2.5f;
    p = 2.81022636e-08f;
    p = fmaf(p, w, 3.43273939e-07f);
    p = fmaf(p, w, -3.5233877e-06f);
    p = fmaf(p, w, -4.39150654e-06f);
    p = fmaf(p, w, 0.00021858087f);
    p = fmaf(p, w, -0.00125372503f);
    p = fmaf(p, w, -0.00417768164f);
    p = fmaf(p, w, 0.246640727f);
    p = fmaf(p, w, 1.50140941f);
  } else {
    w = sqrtf(w) - 3.0f;
    p = -0.000200214257f;
    p = fmaf(p, w, 0.000100950558f);
    p = fmaf(p, w, 0.00134934322f);
    p = fmaf(p, w, -0.00367342844f);
    p = fmaf(p, w, 0.00573950773f);
    p = fmaf(p, w, -0.0076224613f);
    p = fmaf(p, w, 0.00943887047f);
    p = fmaf(p, w, 1.00167406f);
    p = fmaf(p, w, 2.83297682f);
  }
  return 1.41421354f * (p * u);
}

// bf16 round-to-nearest-even (returns 16-bit pattern)
__device__ __forceinline__ uint32_t bf16rne(float x) {
  uint32_t u = __float_as_uint(x);
  return (u + 0x7FFFu + ((u >> 16) & 1u)) >> 16;
}

// fast tanh: Eigen/XLA-style rational approx x*P(x2)/Q(x2), |err|~1e-7 rel.
__device__ __forceinline__ float fast_tanh(float x) {
  x = fmaxf(-7.90531110763549805f, fminf(7.90531110763549805f, x));
  float x2 = x * x;
  float p = -2.76076847742355e-16f;
  p = fmaf(x2, p, 2.00018790482477e-13f);
  p = fmaf(x2, p, -8.60467152213735e-11f);
  p = fmaf(x2, p, 5.12229709037114e-08f);
  p = fmaf(x2, p, 1.48572235717979e-05f);
  p = fmaf(x2, p, 6.37261928875436e-04f);
  p = fmaf(x2, p, 4.89352455891786e-03f);
  p = x * p;
  float q = 1.19825839466702e-06f;
  q = fmaf(x2, q, 1.18534705686654e-04f);
  q = fmaf(x2, q, 2.26843774817441e-03f);
  q = fmaf(x2, q, 4.89352518554385e-03f);
  return p * __builtin_amdgcn_rcpf(q);
}

// ---------------- prep: split+swizzle weights; init mean/std ----------------
__global__ __launch_bounds__(256) void k_prep(const float* Wb, const float* Ws_,
                                              const float* Wa, const float* Wz,
                                              const float* Wr, float* ws) {
  int i = blockIdx.x * 256 + threadIdx.x;
  uint32_t* wsu = (uint32_t*)ws;
  if (i < 53248) {
    int d = i & 3; int t = i >> 2;
    int lane = t & 63; t >>= 6;
    int ks = t & 7; t >>= 3;
    int nt = t % 13; int hl = t / 13;
    int col = nt * 16 + (lane & 15);
    int kb = ks * 32 + (lane >> 4) * 8 + d * 2;
    uint32_t out = 0;
    for (int e = 0; e < 2; ++e) {
      int k = kb + e;
      float v = 0.f;
      if (col < 200) {
        if (k < 200)      v = Wb[k * 200 + col];
        else if (k < 230) v = Ws_[(k - 200) * 200 + col];
        else if (k < 236) v = Wa[(k - 230) * 200 + col];
      }
      uint32_t hi = bf16rne(v);
      float hf = __uint_as_float(hi << 16);
      uint32_t lo = bf16rne(v - hf);
      uint32_t bits = (hl == 0) ? hi : lo;
      out |= (bits & 0xFFFFu) << (16 * e);
    }
    wsu[OFF_WSW + i] = out;
  } else if (i < 60416) {
    int j = i - 53248;
    int d = j & 3; int t = j >> 2;
    int lane = t & 63; t >>= 6;
    int ks = t % 7; t /= 7;
    int nt = t & 1; int hl = t >> 1;
    int col = nt * 16 + (lane & 15);
    int kb = ks * 32 + (lane >> 4) * 8 + d * 2;
    uint32_t out = 0;
    for (int e = 0; e < 2; ++e) {
      int k = kb + e;
      float v = 0.f;
      if (k < 200) {
        if (col < 30)       v = Wz[k * 30 + col];
        else if (col == 30) v = Wr[k];       // merged reward: h·Wr via col 30
      }
      uint32_t hi = bf16rne(v);
      float hf = __uint_as_float(hi << 16);
      uint32_t lo = bf16rne(v - hf);
      uint32_t bits = (hl == 0) ? hi : lo;
      out |= (bits & 0xFFFFu) << (16 * e);
    }
    wsu[OFF_WZSW + j] = out;
  } else if (i >= 64512 && i < 66048) {
    ws[i] = 0.f;   // mean
  } else if (i >= 66048 && i < 67584) {
    ws[i] = 1.f;   // std
  }
}

// ---------------- full 12-step rollout via split-bf16 MFMA (3-pass) ----------------
// R16 structure with the t=0 garbage-read fix: buf1's [200..236) is zeroed at
// init so phase C's ks 5/6 fragments at t=0 read exact zeros (x0 weights)
// instead of UNINITIALIZED LDS (NaN x 0 = NaN was the R16 failure).
// Phases: A(read R)+B(write W) |bar1| C(read W) |bar2| D(write W) |bar3|.
__global__ __launch_bounds__(256) void k_roll(float* __restrict__ ws,
                                              const float* __restrict__ belief,
                                              const float* __restrict__ state,
                                              const float* __restrict__ bbp,
                                              const float* __restrict__ bzp,
                                              const float* __restrict__ brp,
                                              const float* __restrict__ wrp,
                                              uint32_t f0, uint32_t f1) {
  __shared__ unsigned short xh[2 * XS];     // bf16 hi, double-buffered
  __shared__ unsigned short xl[2 * XS];     // bf16 lo
  __shared__ float rp[4][16];               // per-wave reward partials

  const int tid = threadIdx.x;
  const int wv = tid >> 6;
  const int ln = tid & 63;
  const int r = ln & 15;
  const int kh = ln >> 4;
  const int grow0 = blockIdx.x * 32;
  const uint32_t* __restrict__ wsu = (const uint32_t*)ws;

  // stage-1 role (R7/R10 mapping)
  const int NT  = (wv == 0) ? 4 : 3;
  const int ntb = (wv == 0) ? 0 : (1 + wv * 3);
  // stage-2 role
  const int m2 = wv & 1, j2 = wv >> 1;

  float bbv[4];
#pragma unroll
  for (int j = 0; j < 4; ++j) {
    int col = (ntb + j) * 16 + r;
    bbv[j] = (j < NT && col < 200) ? bbp[col] : 0.f;
  }
  float bzz;
  {
    int col = j2 * 16 + r;
    bzz = (col < 30) ? bzp[col] : 0.f;
  }
  const float wr_s = (j2 == 0) ? wrp[200 + r] : ((r < 14) ? wrp[216 + r] : 0.f);
  const float br0 = brp[0];

  // init buf0: k<200 belief, 200..230 state; zero [236..256) both buffers;
  // zero buf1 [200..236) (t=0 phase-C garbage guard — the R16 fix)
  for (int idx = tid; idx < 32 * 256; idx += 256) {
    int row = idx >> 8, k = idx & 255;
    if (k >= 236) {                          // zero pad, both buffers
      xh[row * 280 + k] = 0; xl[row * 280 + k] = 0;
      xh[XS + row * 280 + k] = 0; xl[XS + row * 280 + k] = 0;
      continue;
    }
    if (k >= 200) {                          // buf1 s/act region: zero (fix)
      xh[XS + row * 280 + k] = 0; xl[XS + row * 280 + k] = 0;
    }
    if (k >= 230) continue;                  // buf0 actions written below
    int b = (grow0 + row) / 1000;
    float v = 0.f;
    if (k < 200) v = belief[b * 200 + k];
    else v = state[b * 30 + (k - 200)];
    uint32_t hi = bf16rne(v);
    float hf = __uint_as_float(hi << 16);
    uint32_t lo = bf16rne(v - hf);
    xh[row * 280 + k] = (unsigned short)hi;
    xl[row * 280 + k] = (unsigned short)lo;
  }
  // t=0 actions into buf0: threefry in-kernel (bit-identical PRNG)
  if (tid < 192) {
    int row = tid / 6, a = tid - row * 6;
    int growR = grow0 + row;
    int b = growR / 1000;
    uint32_t idx = (uint32_t)growR * 6u + (uint32_t)a;   // t=0
    uint32_t y0 = 0u, y1 = idx;
    tf2x32(f0, f1, y0, y1);
    float z = bits_to_normal(y0 ^ y1);
    float mu = ws[OFF_MEAN + (size_t)b * 8 + a];
    float sd = ws[OFF_STD + (size_t)b * 8 + a];
    float v = fmaf(sd, z, mu);
    ws[OFF_ACT + (size_t)growR * 8 + a] = v;
    uint32_t hi = bf16rne(v);
    float hf = __uint_as_float(hi << 16);
    uint32_t lo = bf16rne(v - hf);
    xh[row * 280 + 230 + a] = (unsigned short)hi;
    xl[row * 280 + 230 + a] = (unsigned short)lo;
  }
  __syncthreads();                           // init complete

  float rps[4] = {0.f, 0.f, 0.f, 0.f};

#pragma unroll 1
  for (int t = 0; t < TT; ++t) {
    const int roff = (t & 1) ? XS : 0;       // read buffer
    const int woff = XS - roff;              // write buffer

    // ---- Phase A: stage-1 MFMA from buf[roff] ----
    f32x4 acc[2][4];
#pragma unroll
    for (int m = 0; m < 2; ++m)
#pragma unroll
      for (int j = 0; j < 4; ++j) {
        f32x4 c = {bbv[j], bbv[j], bbv[j], bbv[j]};
        acc[m][j] = c;
      }

#pragma unroll 2
    for (int ks = 0; ks < 8; ++ks) {
      short8v Ah[2], Al[2];
      const int kbase = ks * 32 + kh * 8;
#pragma unroll
      for (int m = 0; m < 2; ++m) {
        int off = roff + (m * 16 + r) * 280 + kbase;
        Ah[m] = *(const short8v*)&xh[off];
        Al[m] = *(const short8v*)&xl[off];
      }
#pragma unroll
      for (int j = 0; j < 4; ++j) {
        if (j < NT) {
          const int nt = ntb + j;
          const short8v Bh = *(const short8v*)(wsu + OFF_WSW + (((0 * 13 + nt) * 8 + ks) * 64 + ln) * 4);
          const short8v Bl = *(const short8v*)(wsu + OFF_WSW + (((1 * 13 + nt) * 8 + ks) * 64 + ln) * 4);
#pragma unroll
          for (int m = 0; m < 2; ++m) {
            f32x4 c = acc[m][j];
            c = __builtin_amdgcn_mfma_f32_16x16x32_bf16(Ah[m], Bl, c, 0, 0, 0);
            c = __builtin_amdgcn_mfma_f32_16x16x32_bf16(Al[m], Bh, c, 0, 0, 0);
            c = __builtin_amdgcn_mfma_f32_16x16x32_bf16(Ah[m], Bh, c, 0, 0, 0);
            acc[m][j] = c;
          }
        }
      }
    }
    // ---- Phase B (no barrier: writes target buf[woff]) ----
#pragma unroll
    for (int j = 0; j < 4; ++j) {
      int col = (ntb + j) * 16 + r;
      if (j < NT && col < 200) {
#pragma unroll
        for (int m = 0; m < 2; ++m) {
#pragma unroll
          for (int reg = 0; reg < 4; ++reg) {
            int row = m * 16 + kh * 4 + reg;
            float h = fast_tanh(acc[m][j][reg]);
            uint32_t hi = bf16rne(h);
            float hf = __uint_as_float(hi << 16);
            uint32_t lo = bf16rne(h - hf);
            xh[woff + row * 280 + col] = (unsigned short)hi;
            xl[woff + row * 280 + col] = (unsigned short)lo;
          }
        }
      }
    }
    __syncthreads();                         // bar1: h writes complete

    // ---- Phase C: stage-2 MFMA from buf[woff] (h); unit (m2,j2) ----
    f32x4 acc2 = {bzz, bzz, bzz, bzz};
#pragma unroll
    for (int ks = 0; ks < 7; ++ks) {         // K=224; k>=200 weights 0, operand quiescent+finite
      int off = woff + (m2 * 16 + r) * 280 + ks * 32 + kh * 8;
      short8v Ah2 = *(const short8v*)&xh[off];
      short8v Al2 = *(const short8v*)&xl[off];
      const short8v Bh = *(const short8v*)(wsu + OFF_WZSW + (((0 * 2 + j2) * 7 + ks) * 64 + ln) * 4);
      const short8v Bl = *(const short8v*)(wsu + OFF_WZSW + (((1 * 2 + j2) * 7 + ks) * 64 + ln) * 4);
      acc2 = __builtin_amdgcn_mfma_f32_16x16x32_bf16(Ah2, Bl, acc2, 0, 0, 0);
      acc2 = __builtin_amdgcn_mfma_f32_16x16x32_bf16(Al2, Bh, acc2, 0, 0, 0);
      acc2 = __builtin_amdgcn_mfma_f32_16x16x32_bf16(Ah2, Bh, acc2, 0, 0, 0);
    }
    __syncthreads();                         // bar2: all stage-2 reads done

    // ---- Phase D: s writes + reward partial + act(t+1) into buf[woff] ----
    if (j2 == 0) {
#pragma unroll
      for (int reg = 0; reg < 4; ++reg) {
        int row = m2 * 16 + kh * 4 + reg;
        float s = fast_tanh(acc2[reg]);
        uint32_t hi = bf16rne(s);
        float hf = __uint_as_float(hi << 16);
        uint32_t lo = bf16rne(s - hf);
        xh[woff + row * 280 + 200 + r] = (unsigned short)hi;
        xl[woff + row * 280 + 200 + r] = (unsigned short)lo;
        rps[reg] = fmaf(s, wr_s, rps[reg]);
      }
    } else {
      if (r < 14) {
#pragma unroll
        for (int reg = 0; reg < 4; ++reg) {
          int row = m2 * 16 + kh * 4 + reg;
          float s = fast_tanh(acc2[reg]);
          uint32_t hi = bf16rne(s);
          float hf = __uint_as_float(hi << 16);
          uint32_t lo = bf16rne(s - hf);
          xh[woff + row * 280 + 216 + r] = (unsigned short)hi;
          xl[woff + row * 280 + 216 + r] = (unsigned short)lo;
          rps[reg] = fmaf(s, wr_s, rps[reg]);
        }
      } else if (r == 14) {
        // col 30 = h·Wr (raw, no tanh) — the merged reward term
#pragma unroll
        for (int reg = 0; reg < 4; ++reg) rps[reg] += acc2[reg];
      }
    }
    // actions for t+1 (threefry, bit-identical; write buf[woff] + global ACT)
    if (t + 1 < TT && tid < 192) {
      int row = tid / 6, a = tid - row * 6;
      int growR = grow0 + row;
      int b = growR / 1000;
      uint32_t idx = (uint32_t)((t + 1) * NROWS + growR) * 6u + (uint32_t)a;
      uint32_t y0 = 0u, y1 = idx;
      tf2x32(f0, f1, y0, y1);
      float z = bits_to_normal(y0 ^ y1);
      float mu = ws[OFF_MEAN + (((size_t)(t + 1) * 16 + b) * 8 + a)];
      float sd = ws[OFF_STD + (((size_t)(t + 1) * 16 + b) * 8 + a)];
      float v = fmaf(sd, z, mu);
      ws[OFF_ACT + ((size_t)(t + 1) * NROWS + growR) * 8 + a] = v;
      uint32_t hi = bf16rne(v);
      float hf = __uint_as_float(hi << 16);
      uint32_t lo = bf16rne(v - hf);
      xh[woff + row * 280 + 230 + a] = (unsigned short)hi;
      xl[woff + row * 280 + 230 + a] = (unsigned short)lo;
    }
    __syncthreads();                         // bar3: buf[woff] complete for next A
  }

  // final reward reduction: butterfly over 16-lane groups, combine 2 waves/row
#pragma unroll
  for (int reg = 0; reg < 4; ++reg) {
#pragma unroll
    for (int mk = 1; mk < 16; mk <<= 1)
      rps[reg] += __shfl_xor(rps[reg], mk, 64);
  }
  if (r == 0) {
#pragma unroll
    for (int reg = 0; reg < 4; ++reg)
      rp[wv][kh * 4 + reg] = rps[reg];
  }
  __syncthreads();
  if (tid < 32) {
    int mrow = tid >> 4, lrow = tid & 15;
    ws[OFF_RET + grow0 + tid] = rp[mrow][lrow] + rp[2 + mrow][lrow] + 12.0f * br0;
  }
}

// ---------------- fused selection: bitonic top-k sort + mean/std ----------------
__global__ __launch_bounds__(1024) void k_select(float* ws) {
  __shared__ float sv[1024];
  __shared__ int si[1024];
  const int b = blockIdx.x, tid = threadIdx.x;
  const float* ret = ws + OFF_RET + b * 1000;
  sv[tid] = (tid < 1000) ? ret[tid] : -3.0e38f;
  si[tid] = tid;
  __syncthreads();
  for (int k = 2; k <= 1024; k <<= 1) {
    for (int j = k >> 1; j > 0; j >>= 1) {
      int ixj = tid ^ j;
      if (ixj > tid) {
        float v1 = sv[tid], v2 = sv[ixj];
        int i1 = si[tid], i2 = si[ixj];
        bool gt = (v1 < v2) || (v1 == v2 && i1 > i2);
        bool up = ((tid & k) == 0);
        if (up ? gt : !gt) {
          sv[tid] = v2; sv[ixj] = v1;
          si[tid] = i2; si[ixj] = i1;
        }
      }
      __syncthreads();
    }
  }
  // mean/std per (t,a): one wave per unit (verbatim k_meanstd reduction)
  const int wvS = tid >> 6, lnS = tid & 63;
  for (int u = wvS; u < 72; u += 16) {
    const int t = u / 6, a = u - t * 6;
    const float* act = ws + OFF_ACT + (size_t)t * NROWS * 8;
    const bool h2 = (lnS < 36);
    int c1 = si[lnS];
    float x1 = act[((size_t)b * 1000 + c1) * 8 + a];
    float x2 = 0.f;
    if (h2) { int cc = si[lnS + 64]; x2 = act[((size_t)b * 1000 + cc) * 8 + a]; }
    float s = x1 + x2;
#pragma unroll
    for (int m = 1; m < 64; m <<= 1) s += __shfl_xor(s, m, 64);
    const float mean = s / 100.0f;
    float d = x1 - mean; float qq = d * d;
    if (h2) { float d2 = x2 - mean; qq += d2 * d2; }
#pragma unroll
    for (int m = 1; m < 64; m <<= 1) qq += __shfl_xor(qq, m, 64);
    if (lnS == 0) {
      ws[OFF_MEAN + ((size_t)t * 16 + b) * 8 + a] = mean;
      ws[OFF_STD  + ((size_t)t * 16 + b) * 8 + a] = sqrtf(qq / 100.0f);
    }
  }
}

__global__ void k_out(const float* ws, float* out) {
  int i = threadIdx.x;
  if (i < 96) out[i] = ws[OFF_MEAN + (i / 6) * 8 + (i % 6)];
}

extern "C" void kernel_launch(void* const* d_in, const int* in_sizes, int n_in,
                              void* d_out, int out_size, void* d_ws, size_t ws_size,
                              hipStream_t stream) {
  const float* belief = (const float*)d_in[0];
  const float* state  = (const float*)d_in[1];
  const float* Wb  = (const float*)d_in[2];
  const float* Ws_ = (const float*)d_in[3];
  const float* Wa  = (const float*)d_in[4];
  const float* bb  = (const float*)d_in[5];
  const float* Wz  = (const float*)d_in[6];
  const float* bz  = (const float*)d_in[7];
  const float* Wr  = (const float*)d_in[8];
  const float* br  = (const float*)d_in[9];
  float* ws = (float*)d_ws;   // needs ~6.5 MB

  k_prep<<<264, 256, 0, stream>>>(Wb, Ws_, Wa, Wz, Wr, ws);

  for (int it = 0; it < NITERS; ++it) {
    uint32_t f0 = 0u, f1 = (uint32_t)it;
    tf2x32(0u, 42u, f0, f1);
    k_roll<<<500, 256, 0, stream>>>(ws, belief, state, bb, bz, br, Wr, f0, f1);
    k_select<<<16, 1024, 0, stream>>>(ws);
  }
  k_out<<<1, 128, 0, stream>>>(ws, (float*)d_out);
}

// Round 18
// 1435.528 us; speedup vs baseline: 1.4482x; 1.0504x over previous
//
#include <hip/hip_runtime.h>
#include <stdint.h>

#define TT 12
#define NITERS 10
#define NCAND 1000
#define AD 6
#define BD 16
#define HD 200
#define ZD 30
#define NROWS 16000
#define NELEM 1152000u

// ws layout (u32/float offsets)
#define OFF_WSW  0u          // u32[53248]  W_all split+swizzled B-frags [hl][13][8][64][4]
#define OFF_WZSW 53248u      // u32[7168]   [Wz | Wr_h@col30] [hl][2][7][64][4]
#define OFF_MEAN 64512u      // f32[12][16][8]
#define OFF_STD  66048u      // f32[12][16][8]
#define OFF_ACT  67584u      // f32[12][16000][8]
#define OFF_RET  1603584u    // f32[16000]

typedef __attribute__((ext_vector_type(8))) short short8v;
typedef __attribute__((ext_vector_type(4))) float f32x4;

// ---------------- threefry2x32 (JAX-exact) ----------------
__host__ __device__ __forceinline__ uint32_t tf_rotl(uint32_t x, int r) {
  return (x << r) | (x >> (32 - r));
}
__host__ __device__ __forceinline__ void tf2x32(uint32_t k0, uint32_t k1,
                                                uint32_t& x0, uint32_t& x1) {
  uint32_t k2 = k0 ^ k1 ^ 0x1BD11BDAu;
  x0 += k0; x1 += k1;
  x0 += x1; x1 = tf_rotl(x1, 13); x1 ^= x0;
  x0 += x1; x1 = tf_rotl(x1, 15); x1 ^= x0;
  x0 += x1; x1 = tf_rotl(x1, 26); x1 ^= x0;
  x0 += x1; x1 = tf_rotl(x1,  6); x1 ^= x0;
  x0 += k1; x1 += k2 + 1u;
  x0 += x1; x1 = tf_rotl(x1, 17); x1 ^= x0;
  x0 += x1; x1 = tf_rotl(x1, 29); x1 ^= x0;
  x0 += x1; x1 = tf_rotl(x1, 16); x1 ^= x0;
  x0 += x1; x1 = tf_rotl(x1, 24); x1 ^= x0;
  x0 += k2; x1 += k0 + 2u;
  x0 += x1; x1 = tf_rotl(x1, 13); x1 ^= x0;
  x0 += x1; x1 = tf_rotl(x1, 15); x1 ^= x0;
  x0 += x1; x1 = tf_rotl(x1, 26); x1 ^= x0;
  x0 += x1; x1 = tf_rotl(x1,  6); x1 ^= x0;
  x0 += k0; x1 += k1 + 3u;
  x0 += x1; x1 = tf_rotl(x1, 17); x1 ^= x0;
  x0 += x1; x1 = tf_rotl(x1, 29); x1 ^= x0;
  x0 += x1; x1 = tf_rotl(x1, 16); x1 ^= x0;
  x0 += x1; x1 = tf_rotl(x1, 24); x1 ^= x0;
  x0 += k1; x1 += k2 + 4u;
  x0 += x1; x1 = tf_rotl(x1, 13); x1 ^= x0;
  x0 += x1; x1 = tf_rotl(x1, 15); x1 ^= x0;
  x0 += x1; x1 = tf_rotl(x1, 26); x1 ^= x0;
  x0 += x1; x1 = tf_rotl(x1,  6); x1 ^= x0;
  x0 += k2; x1 += k0 + 5u;
}

__device__ __forceinline__ float bits_to_normal(uint32_t bits) {
  uint32_t fb = (bits >> 9) | 0x3F800000u;
  float f = __uint_as_float(fb) - 1.0f;          // [0,1)
  float u = f * 2.0f - 0.99999994f;
  u = fmaxf(-0.99999994f, u);
  float w = -log1pf(-u * u);
  float p;
  if (w < 5.0f) {
    w = w - 2.5f;
    p = 2.81022636e-08f;
    p = fmaf(p, w, 3.43273939e-07f);
    p = fmaf(p, w, -3.5233877e-06f);
    p = fmaf(p, w, -4.39150654e-06f);
    p = fmaf(p, w, 0.00021858087f);
    p = fmaf(p, w, -0.00125372503f);
    p = fmaf(p, w, -0.00417768164f);
    p = fmaf(p, w, 0.246640727f);
    p = fmaf(p, w, 1.50140941f);
  } else {
    w = sqrtf(w) - 3.0f;
    p = -0.000200214257f;
    p = fmaf(p, w, 0.000100950558f);
    p = fmaf(p, w, 0.00134934322f);
    p = fmaf(p, w, -0.00367342844f);
    p = fmaf(p, w, 0.00573950773f);
    p = fmaf(p, w, -0.0076224613f);
    p = fmaf(p, w, 0.00943887047f);
    p = fmaf(p, w, 1.00167406f);
    p = fmaf(p, w, 2.83297682f);
  }
  return 1.41421354f * (p * u);
}

// bf16 round-to-nearest-even (returns 16-bit pattern)
__device__ __forceinline__ uint32_t bf16rne(float x) {
  uint32_t u = __float_as_uint(x);
  return (u + 0x7FFFu + ((u >> 16) & 1u)) >> 16;
}

// fast tanh: Eigen/XLA-style rational approx x*P(x2)/Q(x2), |err|~1e-7 rel.
__device__ __forceinline__ float fast_tanh(float x) {
  x = fmaxf(-7.90531110763549805f, fminf(7.90531110763549805f, x));
  float x2 = x * x;
  float p = -2.76076847742355e-16f;
  p = fmaf(x2, p, 2.00018790482477e-13f);
  p = fmaf(x2, p, -8.60467152213735e-11f);
  p = fmaf(x2, p, 5.12229709037114e-08f);
  p = fmaf(x2, p, 1.48572235717979e-05f);
  p = fmaf(x2, p, 6.37261928875436e-04f);
  p = fmaf(x2, p, 4.89352455891786e-03f);
  p = x * p;
  float q = 1.19825839466702e-06f;
  q = fmaf(x2, q, 1.18534705686654e-04f);
  q = fmaf(x2, q, 2.26843774817441e-03f);
  q = fmaf(x2, q, 4.89352518554385e-03f);
  return p * __builtin_amdgcn_rcpf(q);
}

// ---------------- prep: split+swizzle weights; init mean/std ----------------
__global__ __launch_bounds__(256) void k_prep(const float* Wb, const float* Ws_,
                                              const float* Wa, const float* Wz,
                                              const float* Wr, float* ws) {
  int i = blockIdx.x * 256 + threadIdx.x;
  uint32_t* wsu = (uint32_t*)ws;
  if (i < 53248) {
    int d = i & 3; int t = i >> 2;
    int lane = t & 63; t >>= 6;
    int ks = t & 7; t >>= 3;
    int nt = t % 13; int hl = t / 13;
    int col = nt * 16 + (lane & 15);
    int kb = ks * 32 + (lane >> 4) * 8 + d * 2;
    uint32_t out = 0;
    for (int e = 0; e < 2; ++e) {
      int k = kb + e;
      float v = 0.f;
      if (col < 200) {
        if (k < 200)      v = Wb[k * 200 + col];
        else if (k < 230) v = Ws_[(k - 200) * 200 + col];
        else if (k < 236) v = Wa[(k - 230) * 200 + col];
      }
      uint32_t hi = bf16rne(v);
      float hf = __uint_as_float(hi << 16);
      uint32_t lo = bf16rne(v - hf);
      uint32_t bits = (hl == 0) ? hi : lo;
      out |= (bits & 0xFFFFu) << (16 * e);
    }
    wsu[OFF_WSW + i] = out;
  } else if (i < 60416) {
    int j = i - 53248;
    int d = j & 3; int t = j >> 2;
    int lane = t & 63; t >>= 6;
    int ks = t % 7; t /= 7;
    int nt = t & 1; int hl = t >> 1;
    int col = nt * 16 + (lane & 15);
    int kb = ks * 32 + (lane >> 4) * 8 + d * 2;
    uint32_t out = 0;
    for (int e = 0; e < 2; ++e) {
      int k = kb + e;
      float v = 0.f;
      if (k < 200) {
        if (col < 30)       v = Wz[k * 30 + col];
        else if (col == 30) v = Wr[k];       // merged reward: h·Wr via col 30
      }
      uint32_t hi = bf16rne(v);
      float hf = __uint_as_float(hi << 16);
      uint32_t lo = bf16rne(v - hf);
      uint32_t bits = (hl == 0) ? hi : lo;
      out |= (bits & 0xFFFFu) << (16 * e);
    }
    wsu[OFF_WZSW + j] = out;
  } else if (i >= 64512 && i < 66048) {
    ws[i] = 0.f;   // mean
  } else if (i >= 66048 && i < 67584) {
    ws[i] = 1.f;   // std
  }
}

// ---------------- full 12-step rollout via split-bf16 MFMA (3-pass) ----------------
// R14 verbatim (proven 1435us, absmax 0.0): 32 rows/block, 4 waves, grid 500,
// single-buffered x, 4 barriers/step:
//   [B0] s1-read |B1| h-write |B2| s2-read |B3| s-write+act(t+1) [B0].
__global__ __launch_bounds__(256) void k_roll(float* __restrict__ ws,
                                              const float* __restrict__ belief,
                                              const float* __restrict__ state,
                                              const float* __restrict__ bbp,
                                              const float* __restrict__ bzp,
                                              const float* __restrict__ brp,
                                              const float* __restrict__ wrp,
                                              uint32_t f0, uint32_t f1) {
  __shared__ unsigned short xh[32 * 280];   // bf16 hi
  __shared__ unsigned short xl[32 * 280];   // bf16 lo
  __shared__ float rp[4][16];               // per-wave reward partials

  const int tid = threadIdx.x;
  const int wv = tid >> 6;
  const int ln = tid & 63;
  const int r = ln & 15;
  const int kh = ln >> 4;
  const int grow0 = blockIdx.x * 32;
  const uint32_t* __restrict__ wsu = (const uint32_t*)ws;

  // stage-1 role (R7/R10 mapping)
  const int NT  = (wv == 0) ? 4 : 3;
  const int ntb = (wv == 0) ? 0 : (1 + wv * 3);
  // stage-2 role
  const int m2 = wv & 1, j2 = wv >> 1;

  float bbv[4];
#pragma unroll
  for (int j = 0; j < 4; ++j) {
    int col = (ntb + j) * 16 + r;
    bbv[j] = (j < NT && col < 200) ? bbp[col] : 0.f;
  }
  float bzz;
  {
    int col = j2 * 16 + r;
    bzz = (col < 30) ? bzp[col] : 0.f;
  }
  const float wr_s = (j2 == 0) ? wrp[200 + r] : ((r < 14) ? wrp[216 + r] : 0.f);
  const float br0 = brp[0];

  // init x: k<200 belief, 200..230 state, 236..256 zero (230..236 by act-gen)
  for (int idx = tid; idx < 32 * 256; idx += 256) {
    int row = idx >> 8, k = idx & 255;
    if (k >= 230 && k < 236) continue;      // actions written below (disjoint)
    int b = (grow0 + row) / 1000;
    float v = 0.f;
    if (k < 200) v = belief[b * 200 + k];
    else if (k < 230) v = state[b * 30 + (k - 200)];
    uint32_t hi = bf16rne(v);
    float hf = __uint_as_float(hi << 16);
    uint32_t lo = bf16rne(v - hf);
    xh[row * 280 + k] = (unsigned short)hi;
    xl[row * 280 + k] = (unsigned short)lo;
  }
  // t=0 actions: threefry in-kernel (bit-identical to reference PRNG)
  if (tid < 192) {
    int row = tid / 6, a = tid - row * 6;
    int growR = grow0 + row;
    int b = growR / 1000;
    uint32_t idx = (uint32_t)growR * 6u + (uint32_t)a;   // t=0
    uint32_t y0 = 0u, y1 = idx;
    tf2x32(f0, f1, y0, y1);
    float z = bits_to_normal(y0 ^ y1);
    float mu = ws[OFF_MEAN + (size_t)b * 8 + a];
    float sd = ws[OFF_STD + (size_t)b * 8 + a];
    float v = fmaf(sd, z, mu);
    ws[OFF_ACT + (size_t)growR * 8 + a] = v;
    uint32_t hi = bf16rne(v);
    float hf = __uint_as_float(hi << 16);
    uint32_t lo = bf16rne(v - hf);
    xh[row * 280 + 230 + a] = (unsigned short)hi;
    xl[row * 280 + 230 + a] = (unsigned short)lo;
  }
  __syncthreads();                           // B0(t=0): all writes complete

  float rps[4] = {0.f, 0.f, 0.f, 0.f};

#pragma unroll 1
  for (int t = 0; t < TT; ++t) {
    // ---- Phase A: stage 1 reads; h = x @ W_all + bb; 2 M-tiles x NT N-tiles ----
    f32x4 acc[2][4];
#pragma unroll
    for (int m = 0; m < 2; ++m)
#pragma unroll
      for (int j = 0; j < 4; ++j) {
        f32x4 c = {bbv[j], bbv[j], bbv[j], bbv[j]};
        acc[m][j] = c;
      }

#pragma unroll 2
    for (int ks = 0; ks < 8; ++ks) {
      short8v Ah[2], Al[2];
      const int kbase = ks * 32 + kh * 8;
#pragma unroll
      for (int m = 0; m < 2; ++m) {
        int off = (m * 16 + r) * 280 + kbase;
        Ah[m] = *(const short8v*)&xh[off];
        Al[m] = *(const short8v*)&xl[off];
      }
#pragma unroll
      for (int j = 0; j < 4; ++j) {
        if (j < NT) {
          const int nt = ntb + j;
          const short8v Bh = *(const short8v*)(wsu + OFF_WSW + (((0 * 13 + nt) * 8 + ks) * 64 + ln) * 4);
          const short8v Bl = *(const short8v*)(wsu + OFF_WSW + (((1 * 13 + nt) * 8 + ks) * 64 + ln) * 4);
#pragma unroll
          for (int m = 0; m < 2; ++m) {
            f32x4 c = acc[m][j];
            c = __builtin_amdgcn_mfma_f32_16x16x32_bf16(Ah[m], Bl, c, 0, 0, 0);
            c = __builtin_amdgcn_mfma_f32_16x16x32_bf16(Al[m], Bh, c, 0, 0, 0);
            c = __builtin_amdgcn_mfma_f32_16x16x32_bf16(Ah[m], Bh, c, 0, 0, 0);
            acc[m][j] = c;
          }
        }
      }
    }
    __syncthreads();                         // B1: all stage-1 reads done

    // ---- Phase B: h epilogue writes (D: row=(ln>>4)*4+reg, col=ln&15) ----
#pragma unroll
    for (int j = 0; j < 4; ++j) {
      int col = (ntb + j) * 16 + r;
      if (j < NT && col < 200) {
#pragma unroll
        for (int m = 0; m < 2; ++m) {
#pragma unroll
          for (int reg = 0; reg < 4; ++reg) {
            int row = m * 16 + kh * 4 + reg;
            float h = fast_tanh(acc[m][j][reg]);
            uint32_t hi = bf16rne(h);
            float hf = __uint_as_float(hi << 16);
            uint32_t lo = bf16rne(h - hf);
            xh[row * 280 + col] = (unsigned short)hi;
            xl[row * 280 + col] = (unsigned short)lo;
          }
        }
      }
    }
    __syncthreads();                         // B2: h writes complete

    // ---- Phase C: stage 2 reads; s-preact = h @ [Wz|Wr] + bz; unit (m2,j2) ----
    f32x4 acc2 = {bzz, bzz, bzz, bzz};
#pragma unroll
    for (int ks = 0; ks < 7; ++ks) {         // K=224; k>=200 weights are 0
      int off = (m2 * 16 + r) * 280 + ks * 32 + kh * 8;
      short8v Ah2 = *(const short8v*)&xh[off];
      short8v Al2 = *(const short8v*)&xl[off];
      const short8v Bh = *(const short8v*)(wsu + OFF_WZSW + (((0 * 2 + j2) * 7 + ks) * 64 + ln) * 4);
      const short8v Bl = *(const short8v*)(wsu + OFF_WZSW + (((1 * 2 + j2) * 7 + ks) * 64 + ln) * 4);
      acc2 = __builtin_amdgcn_mfma_f32_16x16x32_bf16(Ah2, Bl, acc2, 0, 0, 0);
      acc2 = __builtin_amdgcn_mfma_f32_16x16x32_bf16(Al2, Bh, acc2, 0, 0, 0);
      acc2 = __builtin_amdgcn_mfma_f32_16x16x32_bf16(Ah2, Bh, acc2, 0, 0, 0);
    }
    __syncthreads();                         // B3: all stage-2 reads done

    // ---- Phase D: s writes + reward partial + act(t+1) gen/write ----
    if (j2 == 0) {
#pragma unroll
      for (int reg = 0; reg < 4; ++reg) {
        int row = m2 * 16 + kh * 4 + reg;
        float s = fast_tanh(acc2[reg]);
        uint32_t hi = bf16rne(s);
        float hf = __uint_as_float(hi << 16);
        uint32_t lo = bf16rne(s - hf);
        xh[row * 280 + 200 + r] = (unsigned short)hi;
        xl[row * 280 + 200 + r] = (unsigned short)lo;
        rps[reg] = fmaf(s, wr_s, rps[reg]);
      }
    } else {
      if (r < 14) {
#pragma unroll
        for (int reg = 0; reg < 4; ++reg) {
          int row = m2 * 16 + kh * 4 + reg;
          float s = fast_tanh(acc2[reg]);
          uint32_t hi = bf16rne(s);
          float hf = __uint_as_float(hi << 16);
          uint32_t lo = bf16rne(s - hf);
          xh[row * 280 + 216 + r] = (unsigned short)hi;
          xl[row * 280 + 216 + r] = (unsigned short)lo;
          rps[reg] = fmaf(s, wr_s, rps[reg]);
        }
      } else if (r == 14) {
        // col 30 = h·Wr (raw, no tanh) — the merged reward term
#pragma unroll
        for (int reg = 0; reg < 4; ++reg) rps[reg] += acc2[reg];
      }
    }
    // actions for t+1 (threefry, bit-identical; write LDS + global ACT)
    if (t + 1 < TT && tid < 192) {
      int row = tid / 6, a = tid - row * 6;
      int growR = grow0 + row;
      int b = growR / 1000;
      uint32_t idx = (uint32_t)((t + 1) * NROWS + growR) * 6u + (uint32_t)a;
      uint32_t y0 = 0u, y1 = idx;
      tf2x32(f0, f1, y0, y1);
      float z = bits_to_normal(y0 ^ y1);
      float mu = ws[OFF_MEAN + (((size_t)(t + 1) * 16 + b) * 8 + a)];
      float sd = ws[OFF_STD + (((size_t)(t + 1) * 16 + b) * 8 + a)];
      float v = fmaf(sd, z, mu);
      ws[OFF_ACT + ((size_t)(t + 1) * NROWS + growR) * 8 + a] = v;
      uint32_t hi = bf16rne(v);
      float hf = __uint_as_float(hi << 16);
      uint32_t lo = bf16rne(v - hf);
      xh[row * 280 + 230 + a] = (unsigned short)hi;
      xl[row * 280 + 230 + a] = (unsigned short)lo;
    }
    __syncthreads();                         // B0(t+1): all writes complete
  }

  // final reward reduction: butterfly over 16-lane groups, combine 2 waves/row
#pragma unroll
  for (int reg = 0; reg < 4; ++reg) {
#pragma unroll
    for (int mk = 1; mk < 16; mk <<= 1)
      rps[reg] += __shfl_xor(rps[reg], mk, 64);
  }
  if (r == 0) {
#pragma unroll
    for (int reg = 0; reg < 4; ++reg)
      rp[wv][kh * 4 + reg] = rps[reg];
  }
  __syncthreads();
  if (tid < 32) {
    int mrow = tid >> 4, lrow = tid & 15;
    ws[OFF_RET + grow0 + tid] = rp[mrow][lrow] + rp[2 + mrow][lrow] + 12.0f * br0;
  }
}

// ---------------- fused selection: bitonic top-k sort + mean/std (+final out) ----------------
__global__ __launch_bounds__(1024) void k_select(float* ws, float* out, int last) {
  __shared__ float sv[1024];
  __shared__ int si[1024];
  const int b = blockIdx.x, tid = threadIdx.x;
  const float* ret = ws + OFF_RET + b * 1000;
  sv[tid] = (tid < 1000) ? ret[tid] : -3.0e38f;
  si[tid] = tid;
  __syncthreads();
  for (int k = 2; k <= 1024; k <<= 1) {
    for (int j = k >> 1; j > 0; j >>= 1) {
      int ixj = tid ^ j;
      if (ixj > tid) {
        float v1 = sv[tid], v2 = sv[ixj];
        int i1 = si[tid], i2 = si[ixj];
        bool gt = (v1 < v2) || (v1 == v2 && i1 > i2);
        bool up = ((tid & k) == 0);
        if (up ? gt : !gt) {
          sv[tid] = v2; sv[ixj] = v1;
          si[tid] = i2; si[ixj] = i1;
        }
      }
      __syncthreads();
    }
  }
  // mean/std per (t,a): one wave per unit (verbatim k_meanstd reduction)
  const int wvS = tid >> 6, lnS = tid & 63;
  for (int u = wvS; u < 72; u += 16) {
    const int t = u / 6, a = u - t * 6;
    const float* act = ws + OFF_ACT + (size_t)t * NROWS * 8;
    const bool h2 = (lnS < 36);
    int c1 = si[lnS];
    float x1 = act[((size_t)b * 1000 + c1) * 8 + a];
    float x2 = 0.f;
    if (h2) { int cc = si[lnS + 64]; x2 = act[((size_t)b * 1000 + cc) * 8 + a]; }
    float s = x1 + x2;
#pragma unroll
    for (int m = 1; m < 64; m <<= 1) s += __shfl_xor(s, m, 64);
    const float mean = s / 100.0f;
    float d = x1 - mean; float qq = d * d;
    if (h2) { float d2 = x2 - mean; qq += d2 * d2; }
#pragma unroll
    for (int m = 1; m < 64; m <<= 1) qq += __shfl_xor(qq, m, 64);
    if (lnS == 0) {
      ws[OFF_MEAN + ((size_t)t * 16 + b) * 8 + a] = mean;
      ws[OFF_STD  + ((size_t)t * 16 + b) * 8 + a] = sqrtf(qq / 100.0f);
      if (last && t == 0) out[b * 6 + a] = mean;   // same bits as MEAN store
    }
  }
}

extern "C" void kernel_launch(void* const* d_in, const int* in_sizes, int n_in,
                              void* d_out, int out_size, void* d_ws, size_t ws_size,
                              hipStream_t stream) {
  const float* belief = (const float*)d_in[0];
  const float* state  = (const float*)d_in[1];
  const float* Wb  = (const float*)d_in[2];
  const float* Ws_ = (const float*)d_in[3];
  const float* Wa  = (const float*)d_in[4];
  const float* bb  = (const float*)d_in[5];
  const float* Wz  = (const float*)d_in[6];
  const float* bz  = (const float*)d_in[7];
  const float* Wr  = (const float*)d_in[8];
  const float* br  = (const float*)d_in[9];
  float* ws = (float*)d_ws;   // needs ~6.5 MB

  k_prep<<<264, 256, 0, stream>>>(Wb, Ws_, Wa, Wz, Wr, ws);

  for (int it = 0; it < NITERS; ++it) {
    uint32_t f0 = 0u, f1 = (uint32_t)it;
    tf2x32(0u, 42u, f0, f1);
    k_roll<<<500, 256, 0, stream>>>(ws, belief, state, bb, bz, br, Wr, f0, f1);
    k_select<<<16, 1024, 0, stream>>>(ws, (float*)d_out, it == NITERS - 1);
  }
}